// Round 5
// baseline (279.937 us; speedup 1.0000x reference)
//
#include <hip/hip_runtime.h>

// ---- problem constants ----
#define BSZ 4
#define SEQ 2048
#define DIM 1024
#define NH  16
#define HD  64
#define QT  128   // q rows per block pass (flash)
#define KT  64    // kv rows per tile (flash)
#define PAD 72    // u16 row stride in flash LDS
#define NKT (DIM / 64)  // 16 K-tiles of 64

typedef float v4f __attribute__((ext_vector_type(4)));
typedef short s8v __attribute__((ext_vector_type(8)));
typedef unsigned short u16;
typedef unsigned short u16x8 __attribute__((ext_vector_type(8)));
typedef unsigned short u16x4 __attribute__((ext_vector_type(4)));
typedef unsigned int u32;
typedef unsigned int u32x2 __attribute__((ext_vector_type(2)));
typedef unsigned int u32x4 __attribute__((ext_vector_type(4)));

__device__ __forceinline__ u16 f2bf(float f) {
  u32 u = __builtin_bit_cast(u32, f);
  u32 r = u + 0x7fffu + ((u >> 16) & 1u);  // RNE
  return (u16)(r >> 16);
}
// single v_cvt_pk_bf16_f32 (RNE) — 1 inst for 2 elems
__device__ __forceinline__ u32 cvtpk(float lo, float hi) {
  u32 r; asm("v_cvt_pk_bf16_f32 %0, %1, %2" : "=v"(r) : "v"(lo), "v"(hi)); return r;
}
__device__ __forceinline__ u16 f2bf1(float f) { return (u16)cvtpk(f, f); }
__device__ __forceinline__ float fast_exp2(float x) {
#if __has_builtin(__builtin_amdgcn_exp2f)
  return __builtin_amdgcn_exp2f(x);
#else
  return exp2f(x);
#endif
}
// async global->LDS, 16B per lane; lds ptr must be wave-uniform (HW adds lane*16)
__device__ __forceinline__ void gll16(const u16* g, u16* l) {
  __builtin_amdgcn_global_load_lds((const __attribute__((address_space(1))) void*)g,
                                   (__attribute__((address_space(3))) void*)l, 16, 0, 0);
}
// raw s_barrier: SIInsertWaitcnts does NOT recognize it -> no forced vmcnt(0) drain.
__device__ __forceinline__ void wg_barrier() { asm volatile("s_barrier" ::: "memory"); }
// s_waitcnt imm: vmcnt[3:0] | expcnt<<4 | lgkmcnt<<8 | vmcnt[5:4]<<14
#define WAITCNT_LGKM0 0xC07F  // lgkmcnt(0),  vm/exp unconstrained
#define WAITCNT_LGKM8 0xC87F  // lgkmcnt(8),  vm/exp unconstrained
#define VMW6 __builtin_amdgcn_s_waitcnt(0xF76);
#define VMW0 __builtin_amdgcn_s_waitcnt(0xF70);
#define SCHEDB __builtin_amdgcn_sched_barrier(0);

// ---------------- cast x (fp32) -> bf16 ----------------
__global__ __launch_bounds__(256) void cast_bf16_kernel(const float* __restrict__ x,
                                                        u16* __restrict__ o, int n4) {
  int i = blockIdx.x * 256 + threadIdx.x;
  if (i >= n4) return;
  v4f v = reinterpret_cast<const v4f*>(x)[i];
  u16x4 r;
  #pragma unroll
  for (int c = 0; c < 4; c++) r[c] = f2bf(v[c]);
  reinterpret_cast<u16x4*>(o)[i] = r;
}

// ---------------- transpose + cast W[k][n] -> Wt[n][k] bf16 ----------------
// z==0 (Wq) folds in 1/sqrt(HD)*log2(e): Q leaves the QKV GEMM pre-scaled.
__global__ __launch_bounds__(256) void transpose_cast_kernel(const float* __restrict__ W0,
                                                             const float* __restrict__ W1,
                                                             const float* __restrict__ W2,
                                                             const float* __restrict__ W3,
                                                             u16* __restrict__ out) {
  const float* W = blockIdx.z == 0 ? W0 : blockIdx.z == 1 ? W1 : blockIdx.z == 2 ? W2 : W3;
  const float scale = (blockIdx.z == 0) ? 0.18033688011112042f : 1.0f;
  u16* T = out + (size_t)blockIdx.z * DIM * DIM;
  __shared__ float tile[32][33];
  int tx = threadIdx.x & 31, ty = threadIdx.x >> 5;
  int bn = blockIdx.x * 32, bk = blockIdx.y * 32;
  #pragma unroll
  for (int r = 0; r < 4; r++) {
    int k = bk + ty + r * 8;
    tile[ty + r * 8][tx] = W[(size_t)k * DIM + bn + tx];
  }
  __syncthreads();
  #pragma unroll
  for (int r = 0; r < 4; r++) {
    int n = bn + ty + r * 8;
    T[(size_t)n * DIM + bk + tx] = f2bf(tile[tx][ty + r * 8] * scale);
  }
}

// ======== 256x128 GEMM core: BK=64, 512 thr = 8 waves 4Mx2N, wave-tile 64x64 ========
// Register-double-buffered, ONE-PHASE-AHEAD ds_reads (the m201 mechanism):
// fragment buffers have fixed roles (afA/bfA = kc0, afB/bfB = kc1). Per K-tile:
//   A(t): issue reads(t,kc1)->bufB | lgkm(8) [reads(t,kc0) done, issued last
//         half-phase, drained under MFMA(t-1,kc1)] | 16 MFMA on bufA. No barrier.
//   B(t): vmcnt(0) [waits ONLY tile t+1's 6 gll16, issued one full K-tile ago —
//         counted wait w/ ~1-tile slack] | barrier (the only one per K-tile) |
//         issue reads(t+1,kc0)->bufA | stage tile t+2 | lgkm(8) [reads(t,kc1)
//         done] | 16 MFMA on bufB.
// Every read batch drains under the PREVIOUS batch's MFMAs -> LDS || MFMA.
// Victim-slot safety: reads of slot s(t-1) are lgkm-confirmed at B(t-1) before
// any wave passes B(t)'s barrier and issues ST(t+2)->s(t+2)=s(t-1).
// Read-after-write: reads(t+1,kc0) issued after B(t)'s barrier; every wave's
// vmcnt(0) before that barrier confirmed its own tile-(t+1) gll16s landed.
// LDS 3-slot (144 KiB): A [3][2kc][8192 u16] @0; B [3][2kc][4096 u16] @49152.
// Unit layout (gll16 lane-linear, conflict-free): chunk g=row>>4 at g*512 u16;
// within chunk lane(sR,sC) at sC*128+sR*8.

#define ST_TILE(t_, s_)                                                           \
  gll16(Ag0 + (t_) * 64,      AW0 + (s_) * 16384);                                \
  gll16(Ag1 + (t_) * 64,      AW1 + (s_) * 16384);                                \
  gll16(Ag0 + (t_) * 64 + 32, AW0 + (s_) * 16384 + 8192);                         \
  gll16(Ag1 + (t_) * 64 + 32, AW1 + (s_) * 16384 + 8192);                         \
  gll16(Bg0 + (t_) * 64,      BW0 + (s_) * 8192);                                 \
  gll16(Bg0 + (t_) * 64 + 32, BW0 + (s_) * 8192 + 4096);

#define MM(AF, BF)                                                                \
  __builtin_amdgcn_s_setprio(1);                                                  \
  _Pragma("unroll") for (int i_ = 0; i_ < 4; i_++)                                \
    _Pragma("unroll") for (int j_ = 0; j_ < 4; j_++)                              \
      acc[i_][j_] = __builtin_amdgcn_mfma_f32_16x16x32_bf16(                      \
          AF[i_], BF[j_], acc[i_][j_], 0, 0, 0);                                  \
  __builtin_amdgcn_s_setprio(0);

// A-phase of tile t (slot s_): prefetch kc1, compute kc0
#define PHA(s_)                                                                   \
  _Pragma("unroll") for (int i_ = 0; i_ < 4; i_++)                                \
    afB[i_] = *(const s8v*)(AL + (s_) * 16384 + 8192 + aRd + i_ * 512);           \
  _Pragma("unroll") for (int j_ = 0; j_ < 4; j_++)                                \
    bfB[j_] = *(const s8v*)(BL + (s_) * 8192 + 4096 + bRd + j_ * 512);            \
  SCHEDB                                                                          \
  __builtin_amdgcn_s_waitcnt(WAITCNT_LGKM8);                                      \
  SCHEDB                                                                          \
  MM(afA, bfA)                                                                    \
  SCHEDB

// B-phase of tile t: sn_ = slot of tile t+1; prefetch (t+1,kc0), compute kc1
#define PHB(sn_, STG)                                                             \
  VMW0                                                                            \
  wg_barrier();                                                                   \
  _Pragma("unroll") for (int i_ = 0; i_ < 4; i_++)                                \
    afA[i_] = *(const s8v*)(AL + (sn_) * 16384 + aRd + i_ * 512);                 \
  _Pragma("unroll") for (int j_ = 0; j_ < 4; j_++)                                \
    bfA[j_] = *(const s8v*)(BL + (sn_) * 8192 + bRd + j_ * 512);                  \
  STG                                                                             \
  SCHEDB                                                                          \
  __builtin_amdgcn_s_waitcnt(WAITCNT_LGKM8);                                      \
  SCHEDB                                                                          \
  MM(afB, bfB)                                                                    \
  SCHEDB

#define GEMM256x128_CORE()                                                        \
  extern __shared__ __align__(16) u16 lds[];                                      \
  const int t = threadIdx.x;                                                      \
  const int lane = t & 63, w = t >> 6;                                            \
  const int waveM = w >> 1, waveN = w & 1;                                        \
  const int quad = lane >> 4, l16 = lane & 15;                                    \
  const int sR = lane & 15, sC = lane >> 4;                                       \
  u16* AL = lds;                                                                  \
  u16* BL = lds + 49152;                                                          \
  v4f acc[4][4];                                                                  \
  _Pragma("unroll") for (int i = 0; i < 4; i++)                                   \
    _Pragma("unroll") for (int j = 0; j < 4; j++)                                 \
      acc[i][j] = (v4f){0.f, 0.f, 0.f, 0.f};                                      \
  const u16* Ag0 = A + (size_t)(m0 + w * 32 + sR) * DIM + sC * 8;                 \
  const u16* Ag1 = Ag0 + 16 * DIM;                                                \
  const u16* Bg0 = Bt + (size_t)(n0 + w * 16 + sR) * DIM + sC * 8;                \
  u16* AW0 = AL + w * 1024;                                                       \
  u16* AW1 = AL + w * 1024 + 512;                                                 \
  u16* BW0 = BL + w * 512;                                                        \
  const int aRd = waveM * 2048 + quad * 128 + l16 * 8;                            \
  const int bRd = waveN * 2048 + quad * 128 + l16 * 8;                            \
  s8v afA[4], bfA[4], afB[4], bfB[4];                                             \
  ST_TILE(0, 0) ST_TILE(1, 1)                                                     \
  VMW6                                                                            \
  wg_barrier();                                                                   \
  _Pragma("unroll") for (int i = 0; i < 4; i++)                                   \
    afA[i] = *(const s8v*)(AL + aRd + i * 512);                                   \
  _Pragma("unroll") for (int j = 0; j < 4; j++)                                   \
    bfA[j] = *(const s8v*)(BL + bRd + j * 512);                                   \
  SCHEDB                                                                          \
  PHA(0)  PHB(1, ST_TILE(2, 2))                                                   \
  PHA(1)  PHB(2, ST_TILE(3, 0))                                                   \
  PHA(2)  PHB(0, ST_TILE(4, 1))                                                   \
  PHA(0)  PHB(1, ST_TILE(5, 2))                                                   \
  PHA(1)  PHB(2, ST_TILE(6, 0))                                                   \
  PHA(2)  PHB(0, ST_TILE(7, 1))                                                   \
  PHA(0)  PHB(1, ST_TILE(8, 2))                                                   \
  PHA(1)  PHB(2, ST_TILE(9, 0))                                                   \
  PHA(2)  PHB(0, ST_TILE(10, 1))                                                  \
  PHA(0)  PHB(1, ST_TILE(11, 2))                                                  \
  PHA(1)  PHB(2, ST_TILE(12, 0))                                                  \
  PHA(2)  PHB(0, ST_TILE(13, 1))                                                  \
  PHA(0)  PHB(1, ST_TILE(14, 2))                                                  \
  PHA(1)  PHB(2, ST_TILE(15, 0))                                                  \
  PHA(2)  PHB(0, )                                                                \
  PHA(0)                                                                          \
  __builtin_amdgcn_s_waitcnt(WAITCNT_LGKM0);                                      \
  SCHEDB                                                                          \
  MM(afB, bfB)

// ---------------- fused QKV GEMM; z=0 -> Q (pre-scaled), z=1 -> K, z=2 -> V^T ----------------
// 768 blocks = exactly 3 full CU epochs. Bijective XCD chunk swizzle (768%8==0):
// each XCD owns 96 consecutive (z, m-slab, n) tiles for L2 A-row + W reuse.
__global__ __launch_bounds__(512, 2) void gemm_qkv(const u16* __restrict__ A, const u16* __restrict__ Wt,
                                                   u16* __restrict__ Qb, u16* __restrict__ Kb,
                                                   u16* __restrict__ Vtg) {
  const int bid = blockIdx.x;
  const int swz = (bid & 7) * 96 + (bid >> 3);
  const int z = swz >> 8;            // 3 x 256 blocks
  const int rem = swz & 255;
  const int m0 = (rem >> 3) * 256;   // 32 m-tiles
  const int n0 = (rem & 7) * 128;    // 8 n-tiles
  const u16* Bt = Wt + (size_t)z * DIM * DIM;
  GEMM256x128_CORE()
  if (z == 2) {
    // write V transposed: Vtg[((b*NH+h)*HD+d)*SEQ + s]
    #pragma unroll
    for (int mi = 0; mi < 4; mi++) {
      #pragma unroll
      for (int ni = 0; ni < 4; ni++) {
        int gm0 = m0 + waveM * 64 + mi * 16 + quad * 4;
        int gn = n0 + waveN * 64 + ni * 16 + l16;
        int b = gm0 >> 11, s0 = gm0 & (SEQ - 1), hh = gn >> 6, d = gn & (HD - 1);
        u32x2 pw;
        pw[0] = cvtpk(acc[mi][ni][0], acc[mi][ni][1]);
        pw[1] = cvtpk(acc[mi][ni][2], acc[mi][ni][3]);
        *(u16x4*)(Vtg + ((size_t)(b * NH + hh) * HD + d) * SEQ + s0) =
            __builtin_bit_cast(u16x4, pw);
      }
    }
  } else {
    u16* C = (z == 0) ? Qb : Kb;
    #pragma unroll
    for (int mi = 0; mi < 4; mi++) {
      #pragma unroll
      for (int ni = 0; ni < 4; ni++) {
        int gn = n0 + waveN * 64 + ni * 16 + l16;
        #pragma unroll
        for (int r = 0; r < 4; r++) {
          int gm = m0 + waveM * 64 + mi * 16 + quad * 4 + r;
          C[(size_t)gm * DIM + gn] = f2bf1(acc[mi][ni][r]);
        }
      }
    }
  }
}

// ---------------- projection GEMM: out = ctx * Wo^T + bias (fp32 out) ----------------
// 256 blocks = exactly 1 CU epoch.
__global__ __launch_bounds__(512, 2) void gemm_proj(const u16* __restrict__ A, const u16* __restrict__ Bt,
                                                    float* __restrict__ Cf, const float* __restrict__ bias) {
  const int bid = blockIdx.x;
  const int swz = (bid & 7) * 32 + (bid >> 3);  // bijective
  const int m0 = (swz >> 3) * 256;
  const int n0 = (swz & 7) * 128;
  GEMM256x128_CORE()
  #pragma unroll
  for (int ni = 0; ni < 4; ni++) {
    int gn = n0 + waveN * 64 + ni * 16 + l16;
    float bv = bias[gn];
    #pragma unroll
    for (int mi = 0; mi < 4; mi++) {
      #pragma unroll
      for (int r = 0; r < 4; r++) {
        int gm = m0 + waveM * 64 + mi * 16 + quad * 4 + r;
        Cf[(size_t)gm * DIM + gn] = acc[mi][ni][r] + bv;
      }
    }
  }
}

// ---------------- MFMA flash attention (causal), transposed scores ----------------
// S^T = K*Q^T (K rows permuted so P^T registers are directly the PV B-fragment).
// Softmax over kv: 16 in-register values + 2 shfl_xor. O^T = Vt*P^T in C-layout.
// Causal balance: block pair {px, 15-px} -> 34 KV-tiles each. Grid (NH, px, BSZ).
// cvt_pk P-pack + defer-max (THR=8, exp2 domain) carried from R1 (verified).
__global__ __launch_bounds__(256, 3) void flash_attn_mfma(const u16* __restrict__ Qb,
                                                          const u16* __restrict__ Kb,
                                                          const u16* __restrict__ Vtg,
                                                          u16* __restrict__ Ob) {
  const int h = blockIdx.x, px = blockIdx.y, bb = blockIdx.z;
  const int t = threadIdx.x;
  const int lane = t & 63, w = t >> 6;
  const int quad = lane >> 4, l16 = lane & 15;

  __shared__ u16 QPs[QT * PAD];  // Q staging, then O^T epilogue bounce
  __shared__ u16 Ks[KT * PAD];   // K tile, rows permuted by pi^-1
  __shared__ u16 Vs[HD * PAD];   // V tile, [d][kv]

  const size_t qkbase = (size_t)bb * SEQ * DIM + h * HD;
  const size_t vbase = ((size_t)bb * NH + h) * (size_t)HD * SEQ;

  const int vrow = t >> 2, scol = (t & 3) * 16;
  const int krow = ((vrow >> 5) + 2 * ((vrow >> 2) & 1)) * 16 + ((vrow >> 3) & 3) * 4 + (vrow & 3);

  for (int pass = 0; pass < 2; pass++) {
    const int qi = (pass == 0) ? px : (SEQ / QT - 1 - px);
    const int q0 = qi * QT;
    const int wq = q0 + w * 32;
    const int ntiles = 2 * qi + 2;

    __syncthreads();  // QPs free (previous pass epilogue complete)

    // stage Q (pure copy; scale folded into Wq)
    {
      const int r = t >> 1, c0 = (t & 1) * 32;
      const u16* src = Qb + qkbase + (size_t)(q0 + r) * DIM + c0;
      #pragma unroll
      for (int ch = 0; ch < 4; ch++)
        *(u16x8*)(QPs + r * PAD + c0 + ch * 8) = *(const u16x8*)(src + ch * 8);
    }
    __syncthreads();

    // Q B-fragments: B[n=q][k=d]
    s8v qf[2][2];
    #pragma unroll
    for (int ni = 0; ni < 2; ni++)
      #pragma unroll
      for (int kc = 0; kc < 2; kc++)
        qf[ni][kc] = *(const s8v*)(QPs + (w * 32 + ni * 16 + l16) * PAD + kc * 32 + quad * 8);

    // preload KV tile 0 into registers
    u16x8 kr0, kr1, vr0, vr1;
    {
      const u16* kp = Kb + qkbase + (size_t)vrow * DIM + scol;
      kr0 = *(const u16x8*)kp; kr1 = *(const u16x8*)(kp + 8);
      const u16* vp = Vtg + vbase + (size_t)vrow * SEQ + scol;
      vr0 = *(const u16x8*)vp; vr1 = *(const u16x8*)(vp + 8);
    }

    float mrun[2] = {-1e30f, -1e30f}, lrun[2] = {0.f, 0.f};
    v4f O[4][2];
    #pragma unroll
    for (int di = 0; di < 4; di++)
      #pragma unroll
      for (int ni = 0; ni < 2; ni++) O[di][ni] = (v4f){0.f, 0.f, 0.f, 0.f};

    for (int it = 0; it < ntiles; ++it) {
      const int kv0 = it * KT;
      __syncthreads();
      *(u16x8*)(Ks + krow * PAD + scol) = kr0;
      *(u16x8*)(Ks + krow * PAD + scol + 8) = kr1;
      *(u16x8*)(Vs + vrow * PAD + scol) = vr0;
      *(u16x8*)(Vs + vrow * PAD + scol + 8) = vr1;
      __syncthreads();
      if (it + 1 < ntiles) {  // prefetch next tile (consumed after next barrier)
        const int nkv = kv0 + KT;
        const u16* kp = Kb + qkbase + (size_t)(nkv + vrow) * DIM + scol;
        kr0 = *(const u16x8*)kp; kr1 = *(const u16x8*)(kp + 8);
        const u16* vp = Vtg + vbase + (size_t)vrow * SEQ + nkv + scol;
        vr0 = *(const u16x8*)vp; vr1 = *(const u16x8*)(vp + 8);
      }
      if (kv0 > wq + 31) continue;  // tile fully masked for this wave

      // ---- S^T = K*Q^T : sc[mi][ni], rows kv (permuted), cols q ----
      v4f sc[4][2];
      #pragma unroll
      for (int mi = 0; mi < 4; mi++)
        #pragma unroll
        for (int ni = 0; ni < 2; ni++) sc[mi][ni] = (v4f){0.f, 0.f, 0.f, 0.f};
      #pragma unroll
      for (int kc = 0; kc < 2; kc++) {
        #pragma unroll
        for (int mi = 0; mi < 4; mi++) {
          s8v kf = *(const s8v*)(Ks + (mi * 16 + l16) * PAD + kc * 32 + quad * 8);
          sc[mi][0] = __builtin_amdgcn_mfma_f32_16x16x32_bf16(kf, qf[0][kc], sc[mi][0], 0, 0, 0);
          sc[mi][1] = __builtin_amdgcn_mfma_f32_16x16x32_bf16(kf, qf[1][kc], sc[mi][1], 0, 0, 0);
        }
      }

      // ---- causal mask: kv_g = kv0 + (mi&1)*32 + quad*8 + (mi>>1)*4 + r ----
      if (kv0 + KT > wq) {
        #pragma unroll
        for (int mi = 0; mi < 4; mi++) {
          const int kvb = kv0 + (mi & 1) * 32 + quad * 8 + (mi >> 1) * 4;
          #pragma unroll
          for (int ni = 0; ni < 2; ni++) {
            const int qg = wq + ni * 16 + l16;
            #pragma unroll
            for (int r = 0; r < 4; r++)
              if (kvb + r > qg) sc[mi][ni][r] = -1e30f;
          }
        }
      }

      // ---- online softmax with defer-max (THR=8, exp2 domain) ----
      float mx[2];
      #pragma unroll
      for (int ni = 0; ni < 2; ni++) {
        float m = -1e30f;
        #pragma unroll
        for (int mi = 0; mi < 4; mi++)
          #pragma unroll
          for (int r = 0; r < 4; r++) m = fmaxf(m, sc[mi][ni][r]);
        m = fmaxf(m, __shfl_xor(m, 16, 64));
        m = fmaxf(m, __shfl_xor(m, 32, 64));
        mx[ni] = m;
      }
      const bool defer = __all((mx[0] <= mrun[0] + 8.f) && (mx[1] <= mrun[1] + 8.f));
      if (!defer) {
        float alpha[2];
        #pragma unroll
        for (int ni = 0; ni < 2; ni++) {
          const float mnew = fmaxf(mrun[ni], mx[ni]);
          alpha[ni] = fast_exp2(mrun[ni] - mnew);
          mrun[ni] = mnew;
          lrun[ni] *= alpha[ni];
        }
        #pragma unroll
        for (int di = 0; di < 4; di++)
          #pragma unroll
          for (int ni = 0; ni < 2; ni++)
            #pragma unroll
            for (int r = 0; r < 4; r++) O[di][ni][r] *= alpha[ni];
      }
      #pragma unroll
      for (int ni = 0; ni < 2; ni++) {
        float rsum = 0.f;
        #pragma unroll
        for (int mi = 0; mi < 4; mi++)
          #pragma unroll
          for (int r = 0; r < 4; r++) {
            float p = fast_exp2(sc[mi][ni][r] - mrun[ni]);
            sc[mi][ni][r] = p;
            rsum += p;
          }
        rsum += __shfl_xor(rsum, 16, 64);
        rsum += __shfl_xor(rsum, 32, 64);
        lrun[ni] += rsum;
      }

      // ---- pack P^T as PV B-frag via v_cvt_pk_bf16_f32 ----
      // pf[ni][kc] lanes j: j=0..3 -> sc[kc][ni][j], j=4..7 -> sc[kc+2][ni][j-4]
      s8v pf[2][2];
      #pragma unroll
      for (int ni = 0; ni < 2; ni++)
        #pragma unroll
        for (int kc = 0; kc < 2; kc++) {
          u32x4 wds;
          wds[0] = cvtpk(sc[kc][ni][0], sc[kc][ni][1]);
          wds[1] = cvtpk(sc[kc][ni][2], sc[kc][ni][3]);
          wds[2] = cvtpk(sc[kc + 2][ni][0], sc[kc + 2][ni][1]);
          wds[3] = cvtpk(sc[kc + 2][ni][2], sc[kc + 2][ni][3]);
          pf[ni][kc] = __builtin_bit_cast(s8v, wds);
        }

      // ---- PV: O^T[d][q] += Vt * P^T ----
      #pragma unroll
      for (int kc = 0; kc < 2; kc++) {
        #pragma unroll
        for (int di = 0; di < 4; di++) {
          s8v vf = *(const s8v*)(Vs + (di * 16 + l16) * PAD + kc * 32 + quad * 8);
          O[di][0] = __builtin_amdgcn_mfma_f32_16x16x32_bf16(vf, pf[0][kc], O[di][0], 0, 0, 0);
          O[di][1] = __builtin_amdgcn_mfma_f32_16x16x32_bf16(vf, pf[1][kc], O[di][1], 0, 0, 0);
        }
      }
    }

    // ---- epilogue: normalize, transpose via LDS (wave-private rows), coalesced write ----
    const float inv0 = 1.f / lrun[0], inv1 = 1.f / lrun[1];
    #pragma unroll
    for (int di = 0; di < 4; di++)
      #pragma unroll
      for (int ni = 0; ni < 2; ni++) {
        const float inv = ni ? inv1 : inv0;
        #pragma unroll
        for (int r = 0; r < 4; r++)
          QPs[(w * 32 + ni * 16 + l16) * PAD + di * 16 + quad * 4 + r] = f2bf1(O[di][ni][r] * inv);
      }
    __syncthreads();
    {
      const int r = t >> 1, c0 = (t & 1) * 32;
      u16* dst = Ob + qkbase + (size_t)(q0 + r) * DIM + c0;
      #pragma unroll
      for (int ch = 0; ch < 4; ch++)
        *(u16x8*)(dst + ch * 8) = *(const u16x8*)(QPs + r * PAD + c0 + ch * 8);
    }
  }
}

// ---------------- launch ----------------
extern "C" void kernel_launch(void* const* d_in, const int* in_sizes, int n_in,
                              void* d_out, int out_size, void* d_ws, size_t ws_size,
                              hipStream_t stream) {
  (void)in_sizes; (void)n_in; (void)out_size; (void)ws_size;
  const float* x  = (const float*)d_in[0];
  const float* Wq = (const float*)d_in[1];
  const float* Wk = (const float*)d_in[2];
  const float* Wv = (const float*)d_in[3];
  const float* Wo = (const float*)d_in[4];
  const float* bo = (const float*)d_in[5];
  float* out = (float*)d_out;

  // raise the dynamic-LDS cap once (144 KiB per GEMM block; gfx950 has 160)
  static bool lds_attr_done = false;
  if (!lds_attr_done) {
    hipFuncSetAttribute(reinterpret_cast<const void*>(gemm_qkv),
                        hipFuncAttributeMaxDynamicSharedMemorySize, 147456);
    hipFuncSetAttribute(reinterpret_cast<const void*>(gemm_proj),
                        hipFuncAttributeMaxDynamicSharedMemorySize, 147456);
    lds_attr_done = true;
  }

  char* ws = (char*)d_ws;
  const size_t MB = 1024ull * 1024ull;
  u16* Xb  = (u16*)(ws);             // 16 MB: x bf16 [8192][1024]
  u16* Wt  = (u16*)(ws + 16 * MB);   //  8 MB: Wq(scaled),Wk,Wv,Wo transposed bf16
  u16* Qb  = (u16*)(ws + 24 * MB);   // 16 MB
  u16* Kb  = (u16*)(ws + 40 * MB);   // 16 MB
  u16* Vtg = (u16*)(ws + 56 * MB);   // 16 MB: V transposed [b][h][d][s]
  u16* Cb  = (u16*)(ws + 72 * MB);   // 16 MB: ctx -> 88 MB total

  const int NTOK = BSZ * SEQ;  // 8192
  const int n4 = NTOK * DIM / 4;
  cast_bf16_kernel<<<(n4 + 255) / 256, 256, 0, stream>>>(x, Xb, n4);
  transpose_cast_kernel<<<dim3(32, 32, 4), 256, 0, stream>>>(Wq, Wk, Wv, Wo, Wt);

  // 3 * (8192/256) * (1024/128) = 768 blocks = 3 clean CU epochs
  gemm_qkv<<<dim3(768), 512, 147456, stream>>>(Xb, Wt, Qb, Kb, Vtg);

  flash_attn_mfma<<<dim3(NH, SEQ / QT / 2, BSZ), 256, 0, stream>>>(Qb, Kb, Vtg, Cb);

  // (8192/256) * (1024/128) = 256 blocks = 1 clean CU epoch
  gemm_proj<<<dim3(256), 512, 147456, stream>>>(Cb, Wt + 3ull * DIM * DIM, out, bo);
}

// Round 6
// 266.650 us; speedup vs baseline: 1.0498x; 1.0498x over previous
//
#include <hip/hip_runtime.h>

// ---- problem constants ----
#define BSZ 4
#define SEQ 2048
#define DIM 1024
#define NH  16
#define HD  64
#define QT  128   // q rows per block pass (flash)
#define KT  64    // kv rows per tile (flash)
#define PAD 72    // u16 row stride in flash LDS

typedef float v4f __attribute__((ext_vector_type(4)));
typedef short s8v __attribute__((ext_vector_type(8)));
typedef unsigned short u16;
typedef unsigned short u16x8 __attribute__((ext_vector_type(8)));
typedef unsigned short u16x4 __attribute__((ext_vector_type(4)));
typedef unsigned int u32;
typedef unsigned int u32x2 __attribute__((ext_vector_type(2)));
typedef unsigned int u32x4 __attribute__((ext_vector_type(4)));

__device__ __forceinline__ u16 f2bf(float f) {
  u32 u = __builtin_bit_cast(u32, f);
  u32 r = u + 0x7fffu + ((u >> 16) & 1u);  // RNE
  return (u16)(r >> 16);
}
// single v_cvt_pk_bf16_f32 (RNE) — 1 inst for 2 elems
__device__ __forceinline__ u32 cvtpk(float lo, float hi) {
  u32 r; asm("v_cvt_pk_bf16_f32 %0, %1, %2" : "=v"(r) : "v"(lo), "v"(hi)); return r;
}
__device__ __forceinline__ u16 f2bf1(float f) { return (u16)cvtpk(f, f); }
__device__ __forceinline__ float fast_exp2(float x) {
#if __has_builtin(__builtin_amdgcn_exp2f)
  return __builtin_amdgcn_exp2f(x);
#else
  return exp2f(x);
#endif
}
// async global->LDS, 16B per lane; lds ptr must be wave-uniform (HW adds lane*16)
__device__ __forceinline__ void gll16(const u16* g, u16* l) {
  __builtin_amdgcn_global_load_lds((const __attribute__((address_space(1))) void*)g,
                                   (__attribute__((address_space(3))) void*)l, 16, 0, 0);
}
// raw s_barrier: SIInsertWaitcnts does NOT recognize it -> no forced vmcnt(0) drain.
__device__ __forceinline__ void wg_barrier() { asm volatile("s_barrier" ::: "memory"); }
// s_waitcnt imm: vmcnt[3:0] | expcnt<<4 | lgkmcnt<<8 | vmcnt[5:4]<<14
#define WAITCNT_LGKM0 0xC07F  // lgkmcnt(0), vm/exp unconstrained
#define VMW8 __builtin_amdgcn_s_waitcnt(0xF78);
#define VMW6 __builtin_amdgcn_s_waitcnt(0xF76);
#define VMW4 __builtin_amdgcn_s_waitcnt(0xF74);
#define VMW0 __builtin_amdgcn_s_waitcnt(0xF70);
#define SCHEDB __builtin_amdgcn_sched_barrier(0);

// ---------------- cast x (fp32) -> bf16 ----------------
__global__ __launch_bounds__(256) void cast_bf16_kernel(const float* __restrict__ x,
                                                        u16* __restrict__ o, int n4) {
  int i = blockIdx.x * 256 + threadIdx.x;
  if (i >= n4) return;
  v4f v = reinterpret_cast<const v4f*>(x)[i];
  u16x4 r;
  #pragma unroll
  for (int c = 0; c < 4; c++) r[c] = f2bf(v[c]);
  reinterpret_cast<u16x4*>(o)[i] = r;
}

// ---------------- transpose + cast W[k][n] -> Wt[n][k] bf16 ----------------
// z==0 (Wq) folds in 1/sqrt(HD)*log2(e): Q leaves the QKV GEMM pre-scaled.
__global__ __launch_bounds__(256) void transpose_cast_kernel(const float* __restrict__ W0,
                                                             const float* __restrict__ W1,
                                                             const float* __restrict__ W2,
                                                             const float* __restrict__ W3,
                                                             u16* __restrict__ out) {
  const float* W = blockIdx.z == 0 ? W0 : blockIdx.z == 1 ? W1 : blockIdx.z == 2 ? W2 : W3;
  const float scale = (blockIdx.z == 0) ? 0.18033688011112042f : 1.0f;
  u16* T = out + (size_t)blockIdx.z * DIM * DIM;
  __shared__ float tile[32][33];
  int tx = threadIdx.x & 31, ty = threadIdx.x >> 5;
  int bn = blockIdx.x * 32, bk = blockIdx.y * 32;
  #pragma unroll
  for (int r = 0; r < 4; r++) {
    int k = bk + ty + r * 8;
    tile[ty + r * 8][tx] = W[(size_t)k * DIM + bn + tx];
  }
  __syncthreads();
  #pragma unroll
  for (int r = 0; r < 4; r++) {
    int n = bn + ty + r * 8;
    T[(size_t)n * DIM + bk + tx] = f2bf(tile[tx][ty + r * 8] * scale);
  }
}

// ============= QKV: 256x256 8-phase core (m201 port), BK=64, 8 waves 2Mx4N =============
// 4 phases per K-tile tau: q1=(kc0,mh0) q2=(kc0,mh1) q3=(kc1,mh0) q4=(kc1,mh1),
// 16 MFMA each (mi 0..3 + mh*4, ni 0..3). B-frags (per kc) read at q1/q3, held
// through q2/q4. Staging units = 16 KB kc-halves (2 gll16/wave): fixed stream
//   q1(t): A1(t+1)   q2(t): B1(t+1)   q3(t): A0(t+2)   q4(t): B0(t+2)
// => stage->consume lead 5-6 phases. vmcnt(6) (3 units in flight) ONLY at
// q2/q4, never 0 in the loop (T4). Landing proofs: vmcnt(6)@q2(t) -> B1(t),
// A1(t) landed before q3(t); vmcnt(6)@q4(t) -> A0(t+1),B0(t+1),A1(t+1) landed
// before q1(t+1). Slot reuse (dbuf = t&1): each unit staged 1-3 phases after
// its prior tenant's last read drained (lgkm(0) before that phase's MFMA,
// barrier between). Prologue: 6 units {A0,B0,A1,B1(0), A0,B0(1)}, vmcnt(8)
// (A0,B0(0) landed), barrier. Tail: stages end at B1(15); vmcnt 6 -> 4 -> 0.
// LDS 128 KiB: A [2 dbuf][2 kc][8192 u16] @0; B same @32768. Unit = 16 chunks
// (16 rows x 32 k = 512 u16); chunk rowgrp*512; in-chunk lane at sC*128+sR*8
// (gll16 lane-linear => conflict-free ds_read_b128, 0 conflicts measured).

#define QST_A(t_, kc_, d_)                                                        \
  gll16(AgLo + (t_) * 64 + (kc_) * 32, ALw + (d_) * 16384 + (kc_) * 8192);        \
  gll16(AgHi + (t_) * 64 + (kc_) * 32, ALw + (d_) * 16384 + (kc_) * 8192 + 4096);
#define QST_B(t_, kc_, d_)                                                        \
  gll16(BgLo + (t_) * 64 + (kc_) * 32, BLw + (d_) * 16384 + (kc_) * 8192);        \
  gll16(BgHi + (t_) * 64 + (kc_) * 32, BLw + (d_) * 16384 + (kc_) * 8192 + 4096);

#define QRDB(d_, kc_)                                                             \
  bfr[0] = *(const s8v*)(BL + (d_) * 16384 + (kc_) * 8192 + (wn * 4 + 0) * 512 + rdo); \
  bfr[1] = *(const s8v*)(BL + (d_) * 16384 + (kc_) * 8192 + (wn * 4 + 1) * 512 + rdo); \
  bfr[2] = *(const s8v*)(BL + (d_) * 16384 + (kc_) * 8192 + (wn * 4 + 2) * 512 + rdo); \
  bfr[3] = *(const s8v*)(BL + (d_) * 16384 + (kc_) * 8192 + (wn * 4 + 3) * 512 + rdo);

#define QPH(d_, kc_, mh_, RDB_, STG_, VMW_)                                       \
  { _Pragma("unroll") for (int i_ = 0; i_ < 4; i_++)                              \
      afr[i_] = *(const s8v*)(AL + (d_) * 16384 + (kc_) * 8192 +                  \
                              (wm * 8 + (mh_) * 4 + i_) * 512 + rdo);             \
    RDB_                                                                          \
    STG_                                                                          \
    SCHEDB                                                                        \
    VMW_                                                                          \
    wg_barrier();                                                                 \
    __builtin_amdgcn_s_waitcnt(WAITCNT_LGKM0);                                    \
    SCHEDB                                                                        \
    __builtin_amdgcn_s_setprio(1);                                                \
    _Pragma("unroll") for (int i_ = 0; i_ < 4; i_++)                              \
      _Pragma("unroll") for (int j_ = 0; j_ < 4; j_++)                            \
        acc[(mh_) * 4 + i_][j_] = __builtin_amdgcn_mfma_f32_16x16x32_bf16(        \
            afr[i_], bfr[j_], acc[(mh_) * 4 + i_][j_], 0, 0, 0);                  \
    __builtin_amdgcn_s_setprio(0);                                                \
    wg_barrier(); }

__global__ __launch_bounds__(512, 2) void gemm_qkv(const u16* __restrict__ A, const u16* __restrict__ Wt,
                                                   u16* __restrict__ Qb, u16* __restrict__ Kb,
                                                   u16* __restrict__ Vtg) {
  // 384 blocks; bijective XCD chunk swizzle (384%8==0): 48 consecutive tiles/XCD.
  const int bid = blockIdx.x;
  const int swz = (bid & 7) * 48 + (bid >> 3);
  const int z = swz >> 7;            // 3 x 128
  const int rem = swz & 127;
  const int m0 = (rem >> 2) * 256;   // 32 m-tiles
  const int n0 = (rem & 3) * 256;    // 4 n-tiles
  const u16* Bt = Wt + (size_t)z * DIM * DIM;

  extern __shared__ __align__(16) u16 lds[];
  const int t = threadIdx.x;
  const int lane = t & 63, w = t >> 6;
  const int wm = w >> 2, wn = w & 3;           // 2M x 4N waves, wave-tile 128x64
  const int quad = lane >> 4, l16 = lane & 15;
  const int sR = lane & 15, sC = lane >> 4;
  u16* AL = lds;
  u16* BL = lds + 32768;
  u16* ALw = AL + w * 512;
  u16* BLw = BL + w * 512;
  const int rdo = quad * 128 + l16 * 8;
  const u16* AgLo = A + (size_t)(m0 + w * 16 + sR) * DIM + sC * 8;
  const u16* AgHi = AgLo + (size_t)128 * DIM;
  const u16* BgLo = Bt + (size_t)(n0 + w * 16 + sR) * DIM + sC * 8;
  const u16* BgHi = BgLo + (size_t)128 * DIM;

  v4f acc[8][4];
  #pragma unroll
  for (int i = 0; i < 8; i++)
    #pragma unroll
    for (int j = 0; j < 4; j++) acc[i][j] = (v4f){0.f, 0.f, 0.f, 0.f};
  s8v afr[4], bfr[4];

  // prologue: A0(0) B0(0) A1(0) B1(0) A0(1) B0(1); vmcnt(8) -> A0,B0(0) landed
  QST_A(0, 0, 0) QST_B(0, 0, 0) QST_A(0, 1, 0) QST_B(0, 1, 0)
  QST_A(1, 0, 1) QST_B(1, 0, 1)
  SCHEDB
  VMW8
  wg_barrier();

  for (int it = 0; it < 7; ++it) {
    const int kt = it * 2;           // tau0 = kt (dbuf0), tau1 = kt+1 (dbuf1)
    QPH(0, 0, 0, QRDB(0, 0), QST_A(kt + 1, 1, 1), )
    QPH(0, 0, 1, ,           QST_B(kt + 1, 1, 1), VMW6)
    QPH(0, 1, 0, QRDB(0, 1), QST_A(kt + 2, 0, 0), )
    QPH(0, 1, 1, ,           QST_B(kt + 2, 0, 0), VMW6)
    QPH(1, 0, 0, QRDB(1, 0), QST_A(kt + 2, 1, 0), )
    QPH(1, 0, 1, ,           QST_B(kt + 2, 1, 0), VMW6)
    QPH(1, 1, 0, QRDB(1, 1), QST_A(kt + 3, 0, 1), )
    QPH(1, 1, 1, ,           QST_B(kt + 3, 0, 1), VMW6)
  }
  // tail: tau=14 (dbuf0) — last stages A1(15), B1(15); then drain 6 -> 4 -> 0
  QPH(0, 0, 0, QRDB(0, 0), QST_A(15, 1, 1), )
  QPH(0, 0, 1, ,           QST_B(15, 1, 1), VMW6)
  QPH(0, 1, 0, QRDB(0, 1), , )
  QPH(0, 1, 1, ,           , VMW4)
  // tau=15 (dbuf1)
  QPH(1, 0, 0, QRDB(1, 0), , )
  QPH(1, 0, 1, ,           , VMW0)
  QPH(1, 1, 0, QRDB(1, 1), , )
  QPH(1, 1, 1, ,           , )

  if (z == 2) {
    // write V transposed: Vtg[((b*NH+h)*HD+d)*SEQ + s]
    #pragma unroll
    for (int mi = 0; mi < 8; mi++) {
      #pragma unroll
      for (int ni = 0; ni < 4; ni++) {
        int gm0 = m0 + wm * 128 + mi * 16 + quad * 4;
        int gn = n0 + wn * 64 + ni * 16 + l16;
        int b = gm0 >> 11, s0 = gm0 & (SEQ - 1), hh = gn >> 6, d = gn & (HD - 1);
        u32x2 pw;
        pw[0] = cvtpk(acc[mi][ni][0], acc[mi][ni][1]);
        pw[1] = cvtpk(acc[mi][ni][2], acc[mi][ni][3]);
        *(u16x4*)(Vtg + ((size_t)(b * NH + hh) * HD + d) * SEQ + s0) =
            __builtin_bit_cast(u16x4, pw);
      }
    }
  } else {
    u16* C = (z == 0) ? Qb : Kb;
    #pragma unroll
    for (int mi = 0; mi < 8; mi++) {
      #pragma unroll
      for (int ni = 0; ni < 4; ni++) {
        int gn = n0 + wn * 64 + ni * 16 + l16;
        #pragma unroll
        for (int r = 0; r < 4; r++) {
          int gm = m0 + wm * 128 + mi * 16 + quad * 4 + r;
          C[(size_t)gm * DIM + gn] = f2bf1(acc[mi][ni][r]);
        }
      }
    }
  }
}

// ============= proj: 256x128 core (R1-measured), BK=64, 8 waves 4Mx2N =============
#define ST_TILE(t_, s_)                                                           \
  gll16(Ag0 + (t_) * 64,      AW0 + (s_) * 16384);                                \
  gll16(Ag1 + (t_) * 64,      AW1 + (s_) * 16384);                                \
  gll16(Ag0 + (t_) * 64 + 32, AW0 + (s_) * 16384 + 8192);                         \
  gll16(Ag1 + (t_) * 64 + 32, AW1 + (s_) * 16384 + 8192);                         \
  gll16(Bg0 + (t_) * 64,      BW0 + (s_) * 8192);                                 \
  gll16(Bg0 + (t_) * 64 + 32, BW0 + (s_) * 8192 + 4096);

#define PH(t_, s_, STAGES, VMW)                                                   \
  { const u16* Ab = AL + (s_) * 16384 + aRd;                                      \
    const u16* Bb = BL + (s_) * 8192 + bRd;                                       \
    s8v af[2][4], bf[2][4];                                                       \
    _Pragma("unroll") for (int kc_ = 0; kc_ < 2; kc_++) {                         \
      _Pragma("unroll") for (int i_ = 0; i_ < 4; i_++)                            \
        af[kc_][i_] = *(const s8v*)(Ab + kc_ * 8192 + i_ * 512);                  \
      _Pragma("unroll") for (int j_ = 0; j_ < 4; j_++)                            \
        bf[kc_][j_] = *(const s8v*)(Bb + kc_ * 4096 + j_ * 512);                  \
    }                                                                             \
    STAGES                                                                        \
    VMW                                                                           \
    wg_barrier();                                                                 \
    __builtin_amdgcn_s_waitcnt(WAITCNT_LGKM0);                                    \
    __builtin_amdgcn_s_setprio(1);                                                \
    _Pragma("unroll") for (int kc_ = 0; kc_ < 2; kc_++)                           \
      _Pragma("unroll") for (int i_ = 0; i_ < 4; i_++)                            \
        _Pragma("unroll") for (int j_ = 0; j_ < 4; j_++)                          \
          acc[i_][j_] = __builtin_amdgcn_mfma_f32_16x16x32_bf16(                  \
              af[kc_][i_], bf[kc_][j_], acc[i_][j_], 0, 0, 0);                    \
    __builtin_amdgcn_s_setprio(0);                                                \
    wg_barrier(); }

__global__ __launch_bounds__(512, 2) void gemm_proj(const u16* __restrict__ A, const u16* __restrict__ Bt,
                                                    float* __restrict__ Cf, const float* __restrict__ bias) {
  const int bid = blockIdx.x;
  const int swz = (bid & 7) * 32 + (bid >> 3);  // 256 blocks, bijective
  const int m0 = (swz >> 3) * 256;
  const int n0 = (swz & 7) * 128;
  extern __shared__ __align__(16) u16 lds[];
  const int t = threadIdx.x;
  const int lane = t & 63, w = t >> 6;
  const int waveM = w >> 1, waveN = w & 1;
  const int quad = lane >> 4, l16 = lane & 15;
  const int sR = lane & 15, sC = lane >> 4;
  u16* AL = lds;
  u16* BL = lds + 49152;
  v4f acc[4][4];
  #pragma unroll
  for (int i = 0; i < 4; i++)
    #pragma unroll
    for (int j = 0; j < 4; j++) acc[i][j] = (v4f){0.f, 0.f, 0.f, 0.f};
  const u16* Ag0 = A + (size_t)(m0 + w * 32 + sR) * DIM + sC * 8;
  const u16* Ag1 = Ag0 + 16 * DIM;
  const u16* Bg0 = Bt + (size_t)(n0 + w * 16 + sR) * DIM + sC * 8;
  u16* AW0 = AL + w * 1024;
  u16* AW1 = AL + w * 1024 + 512;
  u16* BW0 = BL + w * 512;
  const int aRd = waveM * 2048 + quad * 128 + l16 * 8;
  const int bRd = waveN * 2048 + quad * 128 + l16 * 8;
  ST_TILE(0, 0) ST_TILE(1, 1)
  VMW6
  wg_barrier();
  #pragma unroll
  for (int t3 = 0; t3 < 12; t3 += 3) {
    PH(t3 + 0, 0, ST_TILE(t3 + 2, 2), VMW6)
    PH(t3 + 1, 1, ST_TILE(t3 + 3, 0), VMW6)
    PH(t3 + 2, 2, ST_TILE(t3 + 4, 1), VMW6)
  }
  PH(12, 0, ST_TILE(14, 2), VMW6)
  PH(13, 1, ST_TILE(15, 0), VMW6)
  PH(14, 2, , VMW0)
  PH(15, 0, , )
  #pragma unroll
  for (int ni = 0; ni < 4; ni++) {
    int gn = n0 + waveN * 64 + ni * 16 + l16;
    float bv = bias[gn];
    #pragma unroll
    for (int mi = 0; mi < 4; mi++) {
      #pragma unroll
      for (int r = 0; r < 4; r++) {
        int gm = m0 + waveM * 64 + mi * 16 + quad * 4 + r;
        Cf[(size_t)gm * DIM + gn] = acc[mi][ni][r] + bv;
      }
    }
  }
}

// ---------------- MFMA flash attention (causal), transposed scores ----------------
// S^T = K*Q^T (K rows permuted so P^T registers are directly the PV B-fragment).
// Softmax over kv: 16 in-register values + 2 shfl_xor. O^T = Vt*P^T in C-layout.
// Causal balance: block pair {px, 15-px} -> 34 KV-tiles each. Grid (NH, px, BSZ).
// cvt_pk P-pack + defer-max (THR=8, exp2 domain) carried from R1 (verified).
__global__ __launch_bounds__(256, 3) void flash_attn_mfma(const u16* __restrict__ Qb,
                                                          const u16* __restrict__ Kb,
                                                          const u16* __restrict__ Vtg,
                                                          u16* __restrict__ Ob) {
  const int h = blockIdx.x, px = blockIdx.y, bb = blockIdx.z;
  const int t = threadIdx.x;
  const int lane = t & 63, w = t >> 6;
  const int quad = lane >> 4, l16 = lane & 15;

  __shared__ u16 QPs[QT * PAD];  // Q staging, then O^T epilogue bounce
  __shared__ u16 Ks[KT * PAD];   // K tile, rows permuted by pi^-1
  __shared__ u16 Vs[HD * PAD];   // V tile, [d][kv]

  const size_t qkbase = (size_t)bb * SEQ * DIM + h * HD;
  const size_t vbase = ((size_t)bb * NH + h) * (size_t)HD * SEQ;

  const int vrow = t >> 2, scol = (t & 3) * 16;
  const int krow = ((vrow >> 5) + 2 * ((vrow >> 2) & 1)) * 16 + ((vrow >> 3) & 3) * 4 + (vrow & 3);

  for (int pass = 0; pass < 2; pass++) {
    const int qi = (pass == 0) ? px : (SEQ / QT - 1 - px);
    const int q0 = qi * QT;
    const int wq = q0 + w * 32;
    const int ntiles = 2 * qi + 2;

    __syncthreads();  // QPs free (previous pass epilogue complete)

    // stage Q (pure copy; scale folded into Wq)
    {
      const int r = t >> 1, c0 = (t & 1) * 32;
      const u16* src = Qb + qkbase + (size_t)(q0 + r) * DIM + c0;
      #pragma unroll
      for (int ch = 0; ch < 4; ch++)
        *(u16x8*)(QPs + r * PAD + c0 + ch * 8) = *(const u16x8*)(src + ch * 8);
    }
    __syncthreads();

    // Q B-fragments: B[n=q][k=d]
    s8v qf[2][2];
    #pragma unroll
    for (int ni = 0; ni < 2; ni++)
      #pragma unroll
      for (int kc = 0; kc < 2; kc++)
        qf[ni][kc] = *(const s8v*)(QPs + (w * 32 + ni * 16 + l16) * PAD + kc * 32 + quad * 8);

    // preload KV tile 0 into registers
    u16x8 kr0, kr1, vr0, vr1;
    {
      const u16* kp = Kb + qkbase + (size_t)vrow * DIM + scol;
      kr0 = *(const u16x8*)kp; kr1 = *(const u16x8*)(kp + 8);
      const u16* vp = Vtg + vbase + (size_t)vrow * SEQ + scol;
      vr0 = *(const u16x8*)vp; vr1 = *(const u16x8*)(vp + 8);
    }

    float mrun[2] = {-1e30f, -1e30f}, lrun[2] = {0.f, 0.f};
    v4f O[4][2];
    #pragma unroll
    for (int di = 0; di < 4; di++)
      #pragma unroll
      for (int ni = 0; ni < 2; ni++) O[di][ni] = (v4f){0.f, 0.f, 0.f, 0.f};

    for (int it = 0; it < ntiles; ++it) {
      const int kv0 = it * KT;
      __syncthreads();
      *(u16x8*)(Ks + krow * PAD + scol) = kr0;
      *(u16x8*)(Ks + krow * PAD + scol + 8) = kr1;
      *(u16x8*)(Vs + vrow * PAD + scol) = vr0;
      *(u16x8*)(Vs + vrow * PAD + scol + 8) = vr1;
      __syncthreads();
      if (it + 1 < ntiles) {  // prefetch next tile (consumed after next barrier)
        const int nkv = kv0 + KT;
        const u16* kp = Kb + qkbase + (size_t)(nkv + vrow) * DIM + scol;
        kr0 = *(const u16x8*)kp; kr1 = *(const u16x8*)(kp + 8);
        const u16* vp = Vtg + vbase + (size_t)vrow * SEQ + nkv + scol;
        vr0 = *(const u16x8*)vp; vr1 = *(const u16x8*)(vp + 8);
      }
      if (kv0 > wq + 31) continue;  // tile fully masked for this wave

      // ---- S^T = K*Q^T : sc[mi][ni], rows kv (permuted), cols q ----
      v4f sc[4][2];
      #pragma unroll
      for (int mi = 0; mi < 4; mi++)
        #pragma unroll
        for (int ni = 0; ni < 2; ni++) sc[mi][ni] = (v4f){0.f, 0.f, 0.f, 0.f};
      #pragma unroll
      for (int kc = 0; kc < 2; kc++) {
        #pragma unroll
        for (int mi = 0; mi < 4; mi++) {
          s8v kf = *(const s8v*)(Ks + (mi * 16 + l16) * PAD + kc * 32 + quad * 8);
          sc[mi][0] = __builtin_amdgcn_mfma_f32_16x16x32_bf16(kf, qf[0][kc], sc[mi][0], 0, 0, 0);
          sc[mi][1] = __builtin_amdgcn_mfma_f32_16x16x32_bf16(kf, qf[1][kc], sc[mi][1], 0, 0, 0);
        }
      }

      // ---- causal mask: kv_g = kv0 + (mi&1)*32 + quad*8 + (mi>>1)*4 + r ----
      if (kv0 + KT > wq) {
        #pragma unroll
        for (int mi = 0; mi < 4; mi++) {
          const int kvb = kv0 + (mi & 1) * 32 + quad * 8 + (mi >> 1) * 4;
          #pragma unroll
          for (int ni = 0; ni < 2; ni++) {
            const int qg = wq + ni * 16 + l16;
            #pragma unroll
            for (int r = 0; r < 4; r++)
              if (kvb + r > qg) sc[mi][ni][r] = -1e30f;
          }
        }
      }

      // ---- online softmax with defer-max (THR=8, exp2 domain) ----
      float mx[2];
      #pragma unroll
      for (int ni = 0; ni < 2; ni++) {
        float m = -1e30f;
        #pragma unroll
        for (int mi = 0; mi < 4; mi++)
          #pragma unroll
          for (int r = 0; r < 4; r++) m = fmaxf(m, sc[mi][ni][r]);
        m = fmaxf(m, __shfl_xor(m, 16, 64));
        m = fmaxf(m, __shfl_xor(m, 32, 64));
        mx[ni] = m;
      }
      const bool defer = __all((mx[0] <= mrun[0] + 8.f) && (mx[1] <= mrun[1] + 8.f));
      if (!defer) {
        float alpha[2];
        #pragma unroll
        for (int ni = 0; ni < 2; ni++) {
          const float mnew = fmaxf(mrun[ni], mx[ni]);
          alpha[ni] = fast_exp2(mrun[ni] - mnew);
          mrun[ni] = mnew;
          lrun[ni] *= alpha[ni];
        }
        #pragma unroll
        for (int di = 0; di < 4; di++)
          #pragma unroll
          for (int ni = 0; ni < 2; ni++)
            #pragma unroll
            for (int r = 0; r < 4; r++) O[di][ni][r] *= alpha[ni];
      }
      #pragma unroll
      for (int ni = 0; ni < 2; ni++) {
        float rsum = 0.f;
        #pragma unroll
        for (int mi = 0; mi < 4; mi++)
          #pragma unroll
          for (int r = 0; r < 4; r++) {
            float p = fast_exp2(sc[mi][ni][r] - mrun[ni]);
            sc[mi][ni][r] = p;
            rsum += p;
          }
        rsum += __shfl_xor(rsum, 16, 64);
        rsum += __shfl_xor(rsum, 32, 64);
        lrun[ni] += rsum;
      }

      // ---- pack P^T as PV B-frag via v_cvt_pk_bf16_f32 ----
      // pf[ni][kc] lanes j: j=0..3 -> sc[kc][ni][j], j=4..7 -> sc[kc+2][ni][j-4]
      s8v pf[2][2];
      #pragma unroll
      for (int ni = 0; ni < 2; ni++)
        #pragma unroll
        for (int kc = 0; kc < 2; kc++) {
          u32x4 wds;
          wds[0] = cvtpk(sc[kc][ni][0], sc[kc][ni][1]);
          wds[1] = cvtpk(sc[kc][ni][2], sc[kc][ni][3]);
          wds[2] = cvtpk(sc[kc + 2][ni][0], sc[kc + 2][ni][1]);
          wds[3] = cvtpk(sc[kc + 2][ni][2], sc[kc + 2][ni][3]);
          pf[ni][kc] = __builtin_bit_cast(s8v, wds);
        }

      // ---- PV: O^T[d][q] += Vt * P^T ----
      #pragma unroll
      for (int kc = 0; kc < 2; kc++) {
        #pragma unroll
        for (int di = 0; di < 4; di++) {
          s8v vf = *(const s8v*)(Vs + (di * 16 + l16) * PAD + kc * 32 + quad * 8);
          O[di][0] = __builtin_amdgcn_mfma_f32_16x16x32_bf16(vf, pf[0][kc], O[di][0], 0, 0, 0);
          O[di][1] = __builtin_amdgcn_mfma_f32_16x16x32_bf16(vf, pf[1][kc], O[di][1], 0, 0, 0);
        }
      }
    }

    // ---- epilogue: normalize, transpose via LDS (wave-private rows), coalesced write ----
    const float inv0 = 1.f / lrun[0], inv1 = 1.f / lrun[1];
    #pragma unroll
    for (int di = 0; di < 4; di++)
      #pragma unroll
      for (int ni = 0; ni < 2; ni++) {
        const float inv = ni ? inv1 : inv0;
        #pragma unroll
        for (int r = 0; r < 4; r++)
          QPs[(w * 32 + ni * 16 + l16) * PAD + di * 16 + quad * 4 + r] = f2bf1(O[di][ni][r] * inv);
      }
    __syncthreads();
    {
      const int r = t >> 1, c0 = (t & 1) * 32;
      u16* dst = Ob + qkbase + (size_t)(q0 + r) * DIM + c0;
      #pragma unroll
      for (int ch = 0; ch < 4; ch++)
        *(u16x8*)(dst + ch * 8) = *(const u16x8*)(QPs + r * PAD + c0 + ch * 8);
    }
  }
}

// ---------------- launch ----------------
extern "C" void kernel_launch(void* const* d_in, const int* in_sizes, int n_in,
                              void* d_out, int out_size, void* d_ws, size_t ws_size,
                              hipStream_t stream) {
  (void)in_sizes; (void)n_in; (void)out_size; (void)ws_size;
  const float* x  = (const float*)d_in[0];
  const float* Wq = (const float*)d_in[1];
  const float* Wk = (const float*)d_in[2];
  const float* Wv = (const float*)d_in[3];
  const float* Wo = (const float*)d_in[4];
  const float* bo = (const float*)d_in[5];
  float* out = (float*)d_out;

  static bool lds_attr_done = false;
  if (!lds_attr_done) {
    hipFuncSetAttribute(reinterpret_cast<const void*>(gemm_qkv),
                        hipFuncAttributeMaxDynamicSharedMemorySize, 131072);
    hipFuncSetAttribute(reinterpret_cast<const void*>(gemm_proj),
                        hipFuncAttributeMaxDynamicSharedMemorySize, 147456);
    lds_attr_done = true;
  }

  char* ws = (char*)d_ws;
  const size_t MB = 1024ull * 1024ull;
  u16* Xb  = (u16*)(ws);             // 16 MB: x bf16 [8192][1024]
  u16* Wt  = (u16*)(ws + 16 * MB);   //  8 MB: Wq(scaled),Wk,Wv,Wo transposed bf16
  u16* Qb  = (u16*)(ws + 24 * MB);   // 16 MB
  u16* Kb  = (u16*)(ws + 40 * MB);   // 16 MB
  u16* Vtg = (u16*)(ws + 56 * MB);   // 16 MB: V transposed [b][h][d][s]
  u16* Cb  = (u16*)(ws + 72 * MB);   // 16 MB: ctx -> 88 MB total

  const int NTOK = BSZ * SEQ;  // 8192
  const int n4 = NTOK * DIM / 4;
  cast_bf16_kernel<<<(n4 + 255) / 256, 256, 0, stream>>>(x, Xb, n4);
  transpose_cast_kernel<<<dim3(32, 32, 4), 256, 0, stream>>>(Wq, Wk, Wv, Wo, Wt);

  // 3 * (8192/256) * (1024/256) = 384 blocks, 512 thr, 128 KiB LDS
  gemm_qkv<<<dim3(384), 512, 131072, stream>>>(Xb, Wt, Qb, Kb, Vtg);

  flash_attn_mfma<<<dim3(NH, SEQ / QT / 2, BSZ), 256, 0, stream>>>(Qb, Kb, Vtg, Cb);

  // (8192/256) * (1024/128) = 256 blocks = 1 clean CU epoch (R1-measured core)
  gemm_proj<<<dim3(256), 512, 147456, stream>>>(Cb, Wt + 3ull * DIM * DIM, out, bo);
}